// Round 1
// baseline (38335.385 us; speedup 1.0000x reference)
//
#include <hip/hip_runtime.h>
#include <cstddef>

// SafetyReflexSNN: 5-layer LIF SNN, B=128, T=512.
//
// ROUND 12: structural rewrite. Only layer 2 is recurrent (s2_prev @ W2b).
// All feedforward GEMMs (L0, L1, L2a, L3, L4) are batched over ALL T=512
// timesteps into five giant (65536 x N x K) fp32 VALU GEMMs; LIF dynamics
// become per-(b,n) register scans over t. Only the recurrent GEMM runs as
// 512 sequential per-step kernels (K split at the legal 512-panel boundary
// across wave-groups, folded in-block, fused with the LIF).
//
// NUMERICS (inherited from round 11, absmax 0.0): per output element the op
// sequence is IDENTICAL to the passing kernel: ascending-k fmaf chain;
// K=1024 folds once at k=512 via tot=__fadd_rn(tot,pan); final
// __fadd_rn(tot,pan); layer-2 combine = one __fadd_rn(cur2a, accB);
// LIF = __fmul_rn / __fadd_rn / __fsub_rn (no contraction).
//
// Falls back to the round-11 phase-pipelined kernel if ws_size < 537 MB.

#define NB 128
#define NT 512

// ---------------------------------------------------------------------------
// ------------------------- NEW BATCHED-TIME PATH ---------------------------
// ---------------------------------------------------------------------------

#define BIGM 65536  // B*T

// ---- big feedforward GEMM: C[m][o] = sum_k A[m][k]*W[o][k], lda = K ----
// BM=64 (blockIdx.y), BN=128 (blockIdx.x), BK=32, 256 threads, 4m x 8o /thread.

__device__ __forceinline__ void bg_stage(
    float (&As)[2][32][68], float (&Ws)[2][32][132], int b, int sk, int sr,
    const float4& a0, const float4& a1, const float4& w0, const float4& w1,
    const float4& w2, const float4& w3)
{
  As[b][sk+0][sr] = a0.x; As[b][sk+1][sr] = a0.y; As[b][sk+2][sr] = a0.z; As[b][sk+3][sr] = a0.w;
  As[b][sk+0][sr+32] = a1.x; As[b][sk+1][sr+32] = a1.y; As[b][sk+2][sr+32] = a1.z; As[b][sk+3][sr+32] = a1.w;
  Ws[b][sk+0][sr] = w0.x; Ws[b][sk+1][sr] = w0.y; Ws[b][sk+2][sr] = w0.z; Ws[b][sk+3][sr] = w0.w;
  Ws[b][sk+0][sr+32] = w1.x; Ws[b][sk+1][sr+32] = w1.y; Ws[b][sk+2][sr+32] = w1.z; Ws[b][sk+3][sr+32] = w1.w;
  Ws[b][sk+0][sr+64] = w2.x; Ws[b][sk+1][sr+64] = w2.y; Ws[b][sk+2][sr+64] = w2.z; Ws[b][sk+3][sr+64] = w2.w;
  Ws[b][sk+0][sr+96] = w3.x; Ws[b][sk+1][sr+96] = w3.y; Ws[b][sk+2][sr+96] = w3.z; Ws[b][sk+3][sr+96] = w3.w;
}

template<int K, bool FOLD>
__global__ __launch_bounds__(256, 3) void big_gemm(
    const float* __restrict__ A, const float* __restrict__ W,
    float* __restrict__ C, int N)
{
  __shared__ float As[2][32][68];
  __shared__ float Ws[2][32][132];
  const int tid = threadIdx.x;
  const int m0 = blockIdx.y << 6;
  const int o0 = blockIdx.x << 7;
  const int sk = (tid & 7) << 2;   // staging k offset 0,4..28
  const int sr = tid >> 3;         // staging row 0..31
  const int tm = (tid >> 4) << 2;  // compute m 0..60
  const int to = (tid & 15) << 2;  // compute o 0..60 (and +64)

  const float* Ap = A + (size_t)(m0 + sr) * K + sk;
  const float* Wp = W + (size_t)(o0 + sr) * K + sk;
  const size_t R32 = (size_t)32 * K;

  float pan[4][8], tot[4][8];
#pragma unroll
  for (int i = 0; i < 4; ++i)
#pragma unroll
    for (int j = 0; j < 8; ++j) { pan[i][j] = 0.f; tot[i][j] = 0.f; }

  constexpr int NKT = K >> 5;

  // prologue: tile 0 -> buf 0
  {
    float4 a0 = *(const float4*)(Ap);
    float4 a1 = *(const float4*)(Ap + R32);
    float4 w0 = *(const float4*)(Wp);
    float4 w1 = *(const float4*)(Wp + R32);
    float4 w2 = *(const float4*)(Wp + 2 * R32);
    float4 w3 = *(const float4*)(Wp + 3 * R32);
    bg_stage(As, Ws, 0, sk, sr, a0, a1, w0, w1, w2, w3);
  }
  __syncthreads();

  int cb = 0;
  for (int kt = 0; kt < NKT; ++kt) {
    float4 na0, na1, nw0, nw1, nw2, nw3;
    if (kt + 1 < NKT) {  // issue next tile's global loads early (hide latency)
      const float* Ap2 = Ap + ((kt + 1) << 5);
      const float* Wp2 = Wp + ((kt + 1) << 5);
      na0 = *(const float4*)(Ap2);
      na1 = *(const float4*)(Ap2 + R32);
      nw0 = *(const float4*)(Wp2);
      nw1 = *(const float4*)(Wp2 + R32);
      nw2 = *(const float4*)(Wp2 + 2 * R32);
      nw3 = *(const float4*)(Wp2 + 3 * R32);
    }
    if (FOLD && kt == 16) {  // kc-panel boundary at k=512: fold, restart chain
#pragma unroll
      for (int i = 0; i < 4; ++i)
#pragma unroll
        for (int j = 0; j < 8; ++j) {
          tot[i][j] = __fadd_rn(tot[i][j], pan[i][j]);
          pan[i][j] = 0.f;
        }
    }
#pragma unroll
    for (int k = 0; k < 32; ++k) {
      const float4 av  = *(const float4*)&As[cb][k][tm];
      const float4 wv0 = *(const float4*)&Ws[cb][k][to];
      const float4 wv1 = *(const float4*)&Ws[cb][k][to + 64];
      const float aa[4] = {av.x, av.y, av.z, av.w};
      const float ww[8] = {wv0.x, wv0.y, wv0.z, wv0.w, wv1.x, wv1.y, wv1.z, wv1.w};
#pragma unroll
      for (int i = 0; i < 4; ++i)
#pragma unroll
        for (int j = 0; j < 8; ++j)
          pan[i][j] = fmaf(aa[i], ww[j], pan[i][j]);  // one chain per element, ascending k
    }
    __syncthreads();
    if (kt + 1 < NKT) {
      bg_stage(As, Ws, cb ^ 1, sk, sr, na0, na1, nw0, nw1, nw2, nw3);
    }
    __syncthreads();
    cb ^= 1;
  }

  // epilogue: fold last panel, write C
#pragma unroll
  for (int i = 0; i < 4; ++i) {
    float4 r0, r1;
    r0.x = __fadd_rn(tot[i][0], pan[i][0]);
    r0.y = __fadd_rn(tot[i][1], pan[i][1]);
    r0.z = __fadd_rn(tot[i][2], pan[i][2]);
    r0.w = __fadd_rn(tot[i][3], pan[i][3]);
    r1.x = __fadd_rn(tot[i][4], pan[i][4]);
    r1.y = __fadd_rn(tot[i][5], pan[i][5]);
    r1.z = __fadd_rn(tot[i][6], pan[i][6]);
    r1.w = __fadd_rn(tot[i][7], pan[i][7]);
    float* Crow = C + (size_t)(m0 + tm + i) * N + o0 + to;
    *(float4*)Crow = r0;
    *(float4*)(Crow + 64) = r1;
  }
}

// ---- LIF scan over t for feedforward layers: thread = (b, n), v in reg ----
template<int N>
__global__ __launch_bounds__(256) void scan_kernel(
    const float* __restrict__ cur, float* __restrict__ sp,
    float alpha, float vth)
{
  const int idx = blockIdx.x * 256 + threadIdx.x;
  const int b = idx / N;
  const int n = idx & (N - 1);
  const float* cp = cur + (size_t)b * NT * N + n;
  float* op = sp + (size_t)b * NT * N + n;
  float v = 0.f;
#pragma unroll 4
  for (int tt = 0; tt < NT; ++tt) {
    float c = cp[(size_t)tt * N];
    float vv = __fadd_rn(__fmul_rn(alpha, v), c);
    float s = (vv >= vth) ? 1.0f : 0.0f;
    v = __fmul_rn(vv, __fsub_rn(1.0f, s));
    op[(size_t)tt * N] = s;
  }
}

// ---- output-layer scan: spikes -> out, counts in-register ----
__global__ __launch_bounds__(256) void scan_out_kernel(
    const float* __restrict__ cur, float* __restrict__ out)
{
  const int idx = blockIdx.x * 256 + threadIdx.x;  // 16384 = 128*128
  const int b = idx >> 7;
  const int o = idx & 127;
  const float* cp = cur + (size_t)b * NT * 128 + o;
  float* op = out + (size_t)b * NT * 128 + o;
  float v = 0.f, cnt = 0.f;
#pragma unroll 4
  for (int tt = 0; tt < NT; ++tt) {
    float c = cp[(size_t)tt * 128];
    float vv = __fadd_rn(__fmul_rn(0.82f, v), c);
    float s = (vv >= 0.8f) ? 1.0f : 0.0f;
    v = __fmul_rn(vv, __fsub_rn(1.0f, s));
    op[(size_t)tt * 128] = s;
    cnt = __fadd_rn(cnt, s);  // integer-exact
  }
  out[(size_t)128 * NT * 128 + (b << 7) + o] = cnt;
}

// ---- recurrent layer-2 step: cur2b = s2[t-1] @ W2b^T (K=1024, fold@512),
//      fused +cur2a and LIF. 8x64 tile; waves 0-3 = panel k<512, 4-7 = k>=512.
__device__ __forceinline__ void r2_stage(
    float (&As)[2][2][32][12], float (&Ws)[2][2][32][66], int p, int b,
    int ak, int am, int wk, int wr, float a, const float4& w0, const float4& w1)
{
  As[p][b][ak][am] = a;
  Ws[p][b][wk+0][wr] = w0.x; Ws[p][b][wk+1][wr] = w0.y;
  Ws[p][b][wk+2][wr] = w0.z; Ws[p][b][wk+3][wr] = w0.w;
  Ws[p][b][wk+0][wr+32] = w1.x; Ws[p][b][wk+1][wr+32] = w1.y;
  Ws[p][b][wk+2][wr+32] = w1.z; Ws[p][b][wk+3][wr+32] = w1.w;
}

__global__ __launch_bounds__(512, 2) void rec2_kernel(
    const float* __restrict__ cur2a,  // [65536][1024]
    const float* __restrict__ W2b,    // [1024][1024]
    float* __restrict__ S2,           // [65536][1024] (rows b*NT+t)
    float* __restrict__ v2,           // [128][1024]
    int t)
{
  __shared__ float As[2][2][32][12];
  __shared__ float Ws[2][2][32][66];
  __shared__ float fb[256][2];
  const int tid = threadIdx.x;
  const int p = tid >> 8;     // panel (0: k<512, 1: k>=512)
  const int q = tid & 255;
  const int b0 = (blockIdx.x >> 4) << 3;   // 16 b-tiles x 8
  const int o0 = (blockIdx.x & 15) << 6;   // 16 o-tiles x 64
  const int cm = q >> 5;            // compute: own row 0..7
  const int co = (q & 31) << 1;     // compute: own 2 cols
  const int am = q >> 5, ak = q & 31;        // A staging: 1 float
  const int wr = q >> 3, wk = (q & 7) << 2;  // W staging: rows wr, wr+32

  float pan0 = 0.f, pan1 = 0.f;
  if (t > 0) {
    const float* Arow = S2 + ((size_t)(b0 + am) * NT + (t - 1)) * 1024 + p * 512 + ak;
    const float* Wrow = W2b + (size_t)(o0 + wr) * 1024 + p * 512 + wk;
    const size_t WR32 = (size_t)32 * 1024;
    // prologue
    {
      float a = Arow[0];
      float4 w0 = *(const float4*)(Wrow);
      float4 w1 = *(const float4*)(Wrow + WR32);
      r2_stage(As, Ws, p, 0, ak, am, wk, wr, a, w0, w1);
    }
    __syncthreads();
    int cb = 0;
    for (int kt = 0; kt < 16; ++kt) {
      float na; float4 nw0, nw1;
      if (kt < 15) {
        na = Arow[(kt + 1) << 5];
        nw0 = *(const float4*)(Wrow + ((kt + 1) << 5));
        nw1 = *(const float4*)(Wrow + ((kt + 1) << 5) + WR32);
      }
#pragma unroll
      for (int k = 0; k < 32; ++k) {
        float a = As[p][cb][k][cm];
        float2 w = *(const float2*)&Ws[p][cb][k][co];
        pan0 = fmaf(a, w.x, pan0);
        pan1 = fmaf(a, w.y, pan1);
      }
      __syncthreads();
      if (kt < 15) r2_stage(As, Ws, p, cb ^ 1, ak, am, wk, wr, na, nw0, nw1);
      __syncthreads();
      cb ^= 1;
    }
  }
  // fold panels in BLAS order: fadd(fadd(0, pan_low), pan_high)
  if (p == 1) { fb[q][0] = pan0; fb[q][1] = pan1; }
  __syncthreads();
  if (p == 0) {
    float r0 = __fadd_rn(__fadd_rn(0.f, pan0), fb[q][0]);
    float r1 = __fadd_rn(__fadd_rn(0.f, pan1), fb[q][1]);
    const int b = b0 + cm;
    const int o = o0 + co;
    const size_t row = ((size_t)b * NT + t) * 1024;
    float2 ca = *(const float2*)(cur2a + row + o);
    float2 vv2 = *(float2*)(v2 + (size_t)b * 1024 + o);
    // reference: one __fadd_rn combining the two matmuls, W2a result first
    float cin0 = __fadd_rn(ca.x, r0);
    float cin1 = __fadd_rn(ca.y, r1);
    float vva = __fadd_rn(__fmul_rn(0.93f, vv2.x), cin0);
    float sa = (vva >= 0.5f) ? 1.0f : 0.0f;
    vv2.x = __fmul_rn(vva, __fsub_rn(1.0f, sa));
    float vvb = __fadd_rn(__fmul_rn(0.93f, vv2.y), cin1);
    float sb = (vvb >= 0.5f) ? 1.0f : 0.0f;
    vv2.y = __fmul_rn(vvb, __fsub_rn(1.0f, sb));
    *(float2*)(v2 + (size_t)b * 1024 + o) = vv2;
    float2 sv; sv.x = sa; sv.y = sb;
    *(float2*)(S2 + row + o) = sv;
  }
}

__global__ __launch_bounds__(256) void zero_kernel(float* __restrict__ p, int n) {
  int i = blockIdx.x * 256 + threadIdx.x;
  if (i < n) p[i] = 0.f;
}

// ---------------------------------------------------------------------------
// ----------------- FALLBACK: round-11 phase-pipelined path -----------------
// ---------------------------------------------------------------------------

enum : size_t {
  FOFF_V0  = 0,                        // [128][1024]
  FOFF_V1  = FOFF_V0 + 128 * 1024,
  FOFF_V2  = FOFF_V1 + 128 * 1024,
  FOFF_V3  = FOFF_V2 + 128 * 1024,     // [128][512]
  FOFF_VO  = FOFF_V3 + 128 * 512,      // [128][128]
  FOFF_CNT = FOFF_VO + 128 * 128,      // [128][128]
  FOFF_S0  = FOFF_CNT + 128 * 128,     // 2 x [128][1024]
  FOFF_S1  = FOFF_S0 + 2 * 128 * 1024,
  FOFF_S2  = FOFF_S1 + 2 * 128 * 1024,
  FOFF_S3  = FOFF_S2 + 2 * 128 * 1024, // 2 x [128][512]
  WS_FLOATS = FOFF_S3 + 2 * 128 * 512
};

__global__ __launch_bounds__(256) void init_kernel(float* __restrict__ wf) {
  size_t i = (size_t)blockIdx.x * blockDim.x + threadIdx.x;
  size_t stride = (size_t)gridDim.x * blockDim.x;
  for (size_t j = i; j < WS_FLOATS; j += stride) wf[j] = 0.0f;
}

__device__ __forceinline__ bool is_fold(int K, int k0) {
  return (K == 1024) && (k0 == 512);
}

__device__ __forceinline__ void gemm_blas(
    const float* __restrict__ Abase, int Astride,
    const float* __restrict__ Wbase, int K,
    int bBase, int oBase,
    float (&As)[32][33], float (&Ws)[32][33],
    float acc[2][2])
{
  const int tid = threadIdx.x;
  const int ldRow = tid >> 3;
  const int ldK   = (tid & 7) << 2;
  const int tb = (tid & 15) << 1;
  const int to = (tid >> 4) << 1;
  float tot[2][2]  = {{0.f, 0.f}, {0.f, 0.f}};
  float pan[2][2]  = {{0.f, 0.f}, {0.f, 0.f}};
  for (int k0 = 0; k0 < K; k0 += 32) {
    if (is_fold(K, k0)) {
#pragma unroll
      for (int i = 0; i < 2; ++i)
#pragma unroll
        for (int j = 0; j < 2; ++j) {
          tot[i][j] = __fadd_rn(tot[i][j], pan[i][j]);
          pan[i][j] = 0.f;
        }
    }
    float4 av = *(const float4*)(Abase + (size_t)(bBase + ldRow) * Astride + k0 + ldK);
    float4 wv = *(const float4*)(Wbase + (size_t)(oBase + ldRow) * K       + k0 + ldK);
    As[ldK + 0][ldRow] = av.x; As[ldK + 1][ldRow] = av.y;
    As[ldK + 2][ldRow] = av.z; As[ldK + 3][ldRow] = av.w;
    Ws[ldK + 0][ldRow] = wv.x; Ws[ldK + 1][ldRow] = wv.y;
    Ws[ldK + 2][ldRow] = wv.z; Ws[ldK + 3][ldRow] = wv.w;
    __syncthreads();
#pragma unroll
    for (int k = 0; k < 32; ++k) {
      float a0 = As[k][tb], a1 = As[k][tb + 1];
      float w0 = Ws[k][to], w1 = Ws[k][to + 1];
      pan[0][0] = fmaf(a0, w0, pan[0][0]);
      pan[0][1] = fmaf(a0, w1, pan[0][1]);
      pan[1][0] = fmaf(a1, w0, pan[1][0]);
      pan[1][1] = fmaf(a1, w1, pan[1][1]);
    }
    __syncthreads();
  }
#pragma unroll
  for (int i = 0; i < 2; ++i)
#pragma unroll
    for (int j = 0; j < 2; ++j)
      acc[i][j] = __fadd_rn(tot[i][j], pan[i][j]);
}

__global__ __launch_bounds__(256) void phase_kernel(
    const float* __restrict__ x,
    const float* __restrict__ W0, const float* __restrict__ W1,
    const float* __restrict__ W2a, const float* __restrict__ W2b,
    const float* __restrict__ W3, const float* __restrict__ W4,
    float* __restrict__ wf, float* __restrict__ out, int p)
{
  float* counts = wf + FOFF_CNT;
  float* s0 = wf + FOFF_S0;  float* s1 = wf + FOFF_S1;
  float* s2 = wf + FOFF_S2;  float* s3 = wf + FOFF_S3;
  const int cur = p & 1, prev = cur ^ 1;

  const int blk = blockIdx.x;
  int layer, lb, K, N, t;
  if (blk < 128)      { layer = 0; lb = blk;       t = p;     K = 512;  N = 1024; }
  else if (blk < 256) { layer = 1; lb = blk - 128; t = p - 1; K = 1024; N = 1024; }
  else if (blk < 384) { layer = 2; lb = blk - 256; t = p - 2; K = 1024; N = 1024; }
  else if (blk < 448) { layer = 3; lb = blk - 384; t = p - 3; K = 1024; N = 512;  }
  else                { layer = 4; lb = blk - 448; t = p - 4; K = 512;  N = 128;  }
  if (t < 0 || t >= NT) return;

  const int ntO = N >> 5;
  const int bBase = (lb / ntO) << 5;
  const int oBase = (lb % ntO) << 5;

  const float* A; int Astride;
  const float* Wm; float* v; float* sOut = nullptr;
  float alpha, vth;
  switch (layer) {
    case 0: A = x + (size_t)t * 512; Astride = NT * 512; Wm = W0; v = wf + FOFF_V0;
            alpha = 0.9f;  vth = 0.5f; sOut = s0 + (size_t)cur * 128 * 1024; break;
    case 1: A = s0 + (size_t)prev * 128 * 1024; Astride = 1024; Wm = W1; v = wf + FOFF_V1;
            alpha = 0.95f; vth = 0.5f; sOut = s1 + (size_t)cur * 128 * 1024; break;
    case 2: A = s1 + (size_t)prev * 128 * 1024; Astride = 1024; Wm = W2a; v = wf + FOFF_V2;
            alpha = 0.93f; vth = 0.5f; sOut = s2 + (size_t)cur * 128 * 1024; break;
    case 3: A = s2 + (size_t)prev * 128 * 1024; Astride = 1024; Wm = W3; v = wf + FOFF_V3;
            alpha = 0.9f;  vth = 0.5f; sOut = s3 + (size_t)cur * 128 * 512; break;
    default: A = s3 + (size_t)prev * 128 * 512; Astride = 512; Wm = W4; v = wf + FOFF_VO;
            alpha = 0.82f; vth = 0.8f; break;
  }

  __shared__ float As[32][33];
  __shared__ float Ws[32][33];
  float acc[2][2];

  gemm_blas(A, Astride, Wm, K, bBase, oBase, As, Ws, acc);

  float acc2[2][2];
  if (layer == 2) {
    gemm_blas(s2 + (size_t)prev * 128 * 1024, 1024, W2b, 1024, bBase, oBase, As, Ws, acc2);
  }

  const int tid = threadIdx.x;
  const int tb = (tid & 15) << 1;
  const int to = (tid >> 4) << 1;
#pragma unroll
  for (int i = 0; i < 2; ++i) {
#pragma unroll
    for (int j = 0; j < 2; ++j) {
      const int b = bBase + tb + i;
      const int o = oBase + to + j;
      float cur_in = acc[i][j];
      if (layer == 2) cur_in = __fadd_rn(acc[i][j], acc2[i][j]);
      float* vp = v + (size_t)b * N + o;
      float vv = __fadd_rn(__fmul_rn(alpha, *vp), cur_in);
      float s = (vv >= vth) ? 1.0f : 0.0f;
      *vp = __fmul_rn(vv, __fsub_rn(1.0f, s));
      if (layer < 4) {
        sOut[(size_t)b * N + o] = s;
      } else {
        out[(size_t)b * (NT * 128) + (size_t)t * 128 + o] = s;
        counts[b * 128 + o] = __fadd_rn(counts[b * 128 + o], s);
      }
    }
  }
}

__global__ __launch_bounds__(256) void fin_kernel(const float* __restrict__ counts,
                                                  float* __restrict__ out) {
  int i = blockIdx.x * blockDim.x + threadIdx.x;
  if (i < 128 * 128) out[(size_t)128 * NT * 128 + i] = counts[i];
}

// ---------------------------------------------------------------------------
// -------------------------------- launcher ---------------------------------
// ---------------------------------------------------------------------------

extern "C" void kernel_launch(void* const* d_in, const int* in_sizes, int n_in,
                              void* d_out, int out_size, void* d_ws, size_t ws_size,
                              hipStream_t stream) {
  const float* x   = (const float*)d_in[0];
  const float* W0  = (const float*)d_in[1];
  const float* W1  = (const float*)d_in[2];
  const float* W2a = (const float*)d_in[3];
  const float* W2b = (const float*)d_in[4];
  const float* W3  = (const float*)d_in[5];
  const float* W4  = (const float*)d_in[6];
  float* wf  = (float*)d_ws;
  float* out = (float*)d_out;

  // new path needs: CUR (65536x1024 f32) + SP (65536x1024 f32) + v2 (128x1024)
  const size_t CUR_F = (size_t)BIGM * 1024;           // 67,108,864 floats
  const size_t NEED  = (2 * CUR_F + 128 * 1024) * sizeof(float);  // 537.4 MB

  if (ws_size >= NEED) {
    float* CUR = wf;
    float* SP  = wf + CUR_F;
    float* V2  = wf + 2 * CUR_F;

    zero_kernel<<<512, 256, 0, stream>>>(V2, 128 * 1024);

    // L0: cur0 = x @ W0^T   (K=512, no fold)
    big_gemm<512, false><<<dim3(8, 1024), 256, 0, stream>>>(x, W0, CUR, 1024);
    scan_kernel<1024><<<512, 256, 0, stream>>>(CUR, SP, 0.9f, 0.5f);    // s0
    // L1: cur1 = s0 @ W1^T  (K=1024, fold@512)
    big_gemm<1024, true><<<dim3(8, 1024), 256, 0, stream>>>(SP, W1, CUR, 1024);
    scan_kernel<1024><<<512, 256, 0, stream>>>(CUR, SP, 0.95f, 0.5f);   // s1
    // L2a: cur2a = s1 @ W2a^T
    big_gemm<1024, true><<<dim3(8, 1024), 256, 0, stream>>>(SP, W2a, CUR, 1024);
    // L2 recurrent: per-step GEMM + fused LIF; writes s2 into SP rows b*NT+t
    for (int t = 0; t < NT; ++t)
      rec2_kernel<<<256, 512, 0, stream>>>(CUR, W2b, SP, V2, t);
    // L3: cur3 = s2 @ W3^T  (N=512)
    big_gemm<1024, true><<<dim3(4, 1024), 256, 0, stream>>>(SP, W3, CUR, 512);
    scan_kernel<512><<<256, 256, 0, stream>>>(CUR, SP, 0.9f, 0.5f);     // s3
    // L4: cur4 = s3 @ W4^T  (K=512, N=128)
    big_gemm<512, false><<<dim3(1, 1024), 256, 0, stream>>>(SP, W4, CUR, 128);
    scan_out_kernel<<<64, 256, 0, stream>>>(CUR, out);                  // spikes+counts
  } else {
    // fallback: round-11 phase-pipelined path
    init_kernel<<<256, 256, 0, stream>>>(wf);
    for (int p = 0; p < NT + 4; ++p) {
      phase_kernel<<<464, 256, 0, stream>>>(x, W0, W1, W2a, W2b, W3, W4, wf, out, p);
    }
    fin_kernel<<<64, 256, 0, stream>>>(wf + FOFF_CNT, out);
  }
}